// Round 5
// baseline (107.496 us; speedup 1.0000x reference)
//
#include <hip/hip_runtime.h>
#include <math.h>

// GlobalMatch: subsample stride-4 -> per batch 4096 pts x 256 ch,
// all-pairs min distance (a vs b), score = 2*sigmoid(-sqrt(d2min)), 4x4 upsample.
//
// Pipeline: gather/compact(fp16, K-chunked layout) -> fp16 32x32x16 MFMA GEMM
// (A full-K in registers, B dbuf LDS, counted vmcnt, 4 accumulator chains)
// with fused min-reduction -> finalize(score + upsample).

#define BATCH 4
#define CH    256
#define HH    256
#define WW    256
#define NPTS  4096          // 64*64 subsampled points per batch
#define EPSV  1e-6f

typedef _Float16 half8  __attribute__((ext_vector_type(8)));
typedef float    f32x4  __attribute__((ext_vector_type(4)));
typedef float    f32x16 __attribute__((ext_vector_type(16)));

typedef __attribute__((address_space(1))) const void global_cvoid;
typedef __attribute__((address_space(3))) void lds_void;

// ws layout (bytes)
#define AC_OFF   0u                           // fp16 chunks [b][kc(32)][n(4096)] * 16B = 8MB
#define BC_OFF   (8u << 20)                   // same, 8MB
#define A2_OFF   (16u << 20)                  // f32 [b][n]  a2 + 2eps*sa            (64KB)
#define B2_OFF   ((16u << 20) + (64u << 10))  // f32 [b][n]  b2 - 2eps*sb + C*eps^2  (64KB)
#define DP_OFF   ((16u << 20) + (128u << 10)) // f32 [b][n][8] per-(mq,wm) min d2    (512KB)
#define WS_TOTAL ((16u << 20) + (640u << 10))

// ---------------------------------------------------------------- gather
// grid (64 h, 4 b, 2 input), block 256.
__global__ __launch_bounds__(256) void gm_gather(
    const float* __restrict__ srcA, const float* __restrict__ srcB,
    unsigned char* __restrict__ ws)
{
  const int t  = threadIdx.x;
  const int h  = blockIdx.x;
  const int b  = blockIdx.y;
  const int z  = blockIdx.z;               // 0 -> a, 1 -> b
  const int w  = t & 63;
  const int wv = t >> 6;

  const float* src = z ? srcB : srcA;
  unsigned char* dst = ws + (z ? BC_OFF : AC_OFF);
  float* norms = (float*)(ws + (z ? B2_OFF : A2_OFF));
  const float epsSign = z ? -2.0f * EPSV : 2.0f * EPSV;
  const float addC    = z ? (float)CH * EPSV * EPSV : 0.0f;

  const float* rowbase = src + ((size_t)b * CH) * (HH * WW)
                             + (size_t)(h * 4) * WW + (size_t)(w * 4);
  float ssum = 0.0f, ssq = 0.0f;
  #pragma unroll
  for (int i = 0; i < 8; ++i) {
    const int kc = wv * 8 + i;             // 16B chunk index (8 channels)
    half8 hv;
    #pragma unroll
    for (int j = 0; j < 8; ++j) {
      const int c = kc * 8 + j;
      float v = rowbase[(size_t)c * (HH * WW)];
      ssum += v;
      ssq  = fmaf(v, v, ssq);
      hv[j] = (_Float16)v;
    }
    *reinterpret_cast<half8*>(dst + ((size_t)((b * 32 + kc) * NPTS + h * 64 + w)) * 16) = hv;
  }

  __shared__ float red[2][4][64];
  red[0][wv][w] = ssum;
  red[1][wv][w] = ssq;
  __syncthreads();
  if (t < 64) {
    float sm = red[0][0][t] + red[0][1][t] + red[0][2][t] + red[0][3][t];
    float sq = red[1][0][t] + red[1][1][t] + red[1][2][t] + red[1][3][t];
    norms[b * NPTS + h * 64 + t] = fmaf(epsSign, sm, sq) + addC;
  }
}

// ---------------------------------------------------------------- gemm + min
// grid 256 (XCD-chunk swizzled), block 512 (8 waves = 4 n-waves x 2 m-waves).
// Block: 256 n x 1024 m, K=256. A (256x256 fp16 = 128KB) staged once through
// the full LDS, then each wave holds its 64 n-rows x K=256 in af[2][16].
// B streamed as 128m x 256K (64KB) tiles, double-buffered, counted vmcnt(8).
// XOR swizzle: physical = logical ^ ((row&7)<<4). Since rr*512 (bits>=9),
// khalf*16 (bit 4) and kk*32 (bits 5-8) are bit-disjoint, the full-offset
// swizzle factors as base_sw ^ (kk*32) with base_sw = (rr*512+khalf*16)^sw.
// 4 accumulator chains (nf x kk-parity) -> dependent MFMA distance 4 issues.
// MFMA 32x32x16_f16: C/D col=lane&31, row=(r&3)+8*(r>>2)+4*(lane>>5).
__device__ __forceinline__ void stage_b_tile(const unsigned char* __restrict__ Bc,
                                             int b, int mbase,
                                             unsigned char* dst, int t) {
  const int wv = t >> 6;
  #pragma unroll
  for (int r = 0; r < 8; ++r) {
    unsigned x  = (unsigned)(r * 512 + t) * 16;            // dest byte in 64KB tile
    unsigned lb = x ^ (((x >> 9) & 7) << 4);               // logical byte
    unsigned m_l = lb >> 9;                                // 0..127
    unsigned kcb = (lb & 511) >> 4;                        // 0..31
    const unsigned char* srcp =
        Bc + ((size_t)((b * 32 + kcb) * NPTS + mbase + m_l)) * 16;
    __builtin_amdgcn_global_load_lds((global_cvoid*)srcp,
                                     (lds_void*)(dst + (r * 8192 + wv * 1024)),
                                     16, 0, 0);
  }
}

__global__ __launch_bounds__(512, 2) void gm_gemm_min(
    const unsigned char* __restrict__ Ac, const unsigned char* __restrict__ Bc,
    const float* __restrict__ a2p, const float* __restrict__ b2pc,
    float* __restrict__ d2part)
{
  __shared__ __align__(16) unsigned char smem[131072];

  const int t  = threadIdx.x;
  const int l  = t & 63;
  const int wv = t >> 6;                   // 0..7
  const int wn = wv & 3;                   // n-wave 0..3
  const int wm = wv >> 2;                  // m-wave 0..1
  const int ln31  = l & 31;
  const int khalf = l >> 5;

  // bijective XCD-chunk swizzle (256 blocks, 8 XCDs, 32 per chunk)
  const int orig    = blockIdx.x;
  const int logical = (orig & 7) * 32 + (orig >> 3);
  const int ns = logical & 15;             // 16 n-strips
  const int mq = (logical >> 4) & 3;       // 4 m-quarters
  const int b  = logical >> 6;             // 4 batches
  const int nbase  = ns * 256;
  const int mstart = mq * 1024;

  // ---- stage A strip (256 rows x 256 K fp16 = 128KB) into full LDS
  #pragma unroll
  for (int r = 0; r < 16; ++r) {
    unsigned x  = (unsigned)(r * 512 + t) * 16;
    unsigned lb = x ^ (((x >> 9) & 7) << 4);
    unsigned n_l = lb >> 9;                                // 0..255
    unsigned kcb = (lb & 511) >> 4;
    const unsigned char* srcp =
        Ac + ((size_t)((b * 32 + kcb) * NPTS + nbase + n_l)) * 16;
    __builtin_amdgcn_global_load_lds((global_cvoid*)srcp,
                                     (lds_void*)(smem + (r * 8192 + wv * 1024)),
                                     16, 0, 0);
  }
  asm volatile("s_waitcnt vmcnt(0)" ::: "memory");
  __builtin_amdgcn_s_barrier();

  // ---- A fragments: wave's 64 n-rows, full K=256 (128 VGPRs)
  half8 af[2][16];
  #pragma unroll
  for (int nf = 0; nf < 2; ++nf) {
    const unsigned rr      = wn * 64 + nf * 32 + ln31;
    const unsigned base_sw = (rr * 512 + khalf * 16) ^ ((rr & 7) << 4);
    #pragma unroll
    for (int kk = 0; kk < 16; ++kk)
      af[nf][kk] = *reinterpret_cast<const half8*>(smem + (base_sw ^ (kk * 32)));
  }
  asm volatile("s_waitcnt lgkmcnt(0)" ::: "memory");
  __builtin_amdgcn_s_barrier();

  float rmin[2][16];
  #pragma unroll
  for (int nf = 0; nf < 2; ++nf)
    #pragma unroll
    for (int r = 0; r < 16; ++r) rmin[nf][r] = 3.0e38f;

  // ---- main loop: 8 B-tiles of 128 m, double-buffered, counted vmcnt
  stage_b_tile(Bc, b, mstart, smem, t);                    // tile 0 -> buf0
  for (int mt = 0; mt < 8; ++mt) {
    unsigned char* cb = (mt & 1) ? smem + 65536 : smem;    // compute buffer
    unsigned char* nb = (mt & 1) ? smem : smem + 65536;    // prefetch buffer
    if (mt < 7) {
      stage_b_tile(Bc, b, mstart + (mt + 1) * 128, nb, t);
      asm volatile("s_waitcnt vmcnt(8)" ::: "memory");     // tile mt landed
    } else {
      asm volatile("s_waitcnt vmcnt(0)" ::: "memory");
    }
    __builtin_amdgcn_s_barrier();

    const int mbase = mstart + mt * 128;
    #pragma unroll
    for (int ms = 0; ms < 2; ++ms) {
      const unsigned rrB    = wm * 64 + ms * 32 + ln31;
      const unsigned baseB  = (rrB * 512 + khalf * 16) ^ ((rrB & 7) << 4);

      f32x16 a00 = (f32x16)(0.0f);   // nf=0, even kk
      f32x16 a01 = (f32x16)(0.0f);   // nf=0, odd  kk
      f32x16 a10 = (f32x16)(0.0f);   // nf=1, even kk
      f32x16 a11 = (f32x16)(0.0f);   // nf=1, odd  kk

      __builtin_amdgcn_s_setprio(1);
      #pragma unroll
      for (int kp = 0; kp < 8; ++kp) {
        const half8 bf0 = *reinterpret_cast<const half8*>(cb + (baseB ^ ((2 * kp) * 32)));
        a00 = __builtin_amdgcn_mfma_f32_32x32x16_f16(af[0][2 * kp], bf0, a00, 0, 0, 0);
        a10 = __builtin_amdgcn_mfma_f32_32x32x16_f16(af[1][2 * kp], bf0, a10, 0, 0, 0);
        const half8 bf1 = *reinterpret_cast<const half8*>(cb + (baseB ^ ((2 * kp + 1) * 32)));
        a01 = __builtin_amdgcn_mfma_f32_32x32x16_f16(af[0][2 * kp + 1], bf1, a01, 0, 0, 0);
        a11 = __builtin_amdgcn_mfma_f32_32x32x16_f16(af[1][2 * kp + 1], bf1, a11, 0, 0, 0);
      }
      __builtin_amdgcn_s_setprio(0);

      const float bp = b2pc[b * NPTS + mbase + wm * 64 + ms * 32 + ln31];
      #pragma unroll
      for (int r = 0; r < 16; ++r) {
        rmin[0][r] = fminf(rmin[0][r], fmaf(-2.0f, a00[r] + a01[r], bp));
        rmin[1][r] = fminf(rmin[1][r], fmaf(-2.0f, a10[r] + a11[r], bp));
      }
    }
    __builtin_amdgcn_s_barrier();          // cb fully consumed before restage
  }

  // ---- reduce over the 32 col-lanes (m), add a2 term, write partial min
  #pragma unroll
  for (int nf = 0; nf < 2; ++nf)
    #pragma unroll
    for (int r = 0; r < 16; ++r) {
      float v = rmin[nf][r];
      v = fminf(v, __shfl_xor(v, 1, 64));
      v = fminf(v, __shfl_xor(v, 2, 64));
      v = fminf(v, __shfl_xor(v, 4, 64));
      v = fminf(v, __shfl_xor(v, 8, 64));
      v = fminf(v, __shfl_xor(v, 16, 64));
      if (ln31 == 0) {
        const int n = nbase + wn * 64 + nf * 32 + (r & 3) + 8 * (r >> 2) + 4 * khalf;
        d2part[(size_t)(b * NPTS + n) * 8 + mq * 2 + wm] = v + a2p[b * NPTS + n];
      }
    }
}

// ---------------------------------------------------------------- finalize
__global__ __launch_bounds__(256) void gm_finalize(
    const float* __restrict__ d2part, float* __restrict__ out)
{
  const int id = blockIdx.x * 256 + threadIdx.x;      // 0..16383  (b*4096 + n)
  const f32x4 u = *reinterpret_cast<const f32x4*>(d2part + (size_t)id * 8);
  const f32x4 w4 = *reinterpret_cast<const f32x4*>(d2part + (size_t)id * 8 + 4);
  float d2 = fminf(fminf(fminf(u[0], u[1]), fminf(u[2], u[3])),
                   fminf(fminf(w4[0], w4[1]), fminf(w4[2], w4[3])));
  const float l2 = sqrtf(fmaxf(d2, 0.0f));
  const float s  = 2.0f / (1.0f + expf(l2));          // 2*sigmoid(-l2)
  const int b = id >> 12;
  const int n = id & 4095;
  const int h = n >> 6, w = n & 63;
  float4 v = make_float4(s, s, s, s);
  float* obase = out + ((size_t)(b * 256 + h * 4)) * 256 + w * 4;
  #pragma unroll
  for (int i = 0; i < 4; ++i)
    *reinterpret_cast<float4*>(obase + (size_t)i * 256) = v;
}

__global__ void gm_sentinel(float* out) { out[0] = 1.0e6f; }

extern "C" void kernel_launch(void* const* d_in, const int* in_sizes, int n_in,
                              void* d_out, int out_size, void* d_ws, size_t ws_size,
                              hipStream_t stream) {
  const float* a = (const float*)d_in[0];
  const float* b = (const float*)d_in[1];
  float* out = (float*)d_out;
  unsigned char* ws = (unsigned char*)d_ws;

  if (ws_size < (size_t)WS_TOTAL) {
    gm_sentinel<<<1, 1, 0, stream>>>(out);
    return;
  }

  gm_gather<<<dim3(64, 4, 2), 256, 0, stream>>>(a, b, ws);
  gm_gemm_min<<<256, 512, 0, stream>>>(
      ws + AC_OFF, ws + BC_OFF,
      (const float*)(ws + A2_OFF), (const float*)(ws + B2_OFF),
      (float*)(ws + DP_OFF));
  gm_finalize<<<64, 256, 0, stream>>>((const float*)(ws + DP_OFF), out);
}

// Round 6
// 75.178 us; speedup vs baseline: 1.4299x; 1.4299x over previous
//
#include <hip/hip_runtime.h>
#include <math.h>

// GlobalMatch: subsample stride-4 -> per batch 4096 pts x 256 ch,
// all-pairs min distance (a vs b), score = 2*sigmoid(-sqrt(d2min)), 4x4 upsample.
//
// Pipeline: gather/compact(fp16, K-chunked layout) -> fp16 16x16x32 MFMA GEMM
// (R2 structure, split into 2 independent blocks/CU) -> finalize.

#define BATCH 4
#define CH    256
#define HH    256
#define WW    256
#define NPTS  4096          // 64*64 subsampled points per batch
#define EPSV  1e-6f

typedef _Float16 half8  __attribute__((ext_vector_type(8)));
typedef float    f32x4  __attribute__((ext_vector_type(4)));

typedef __attribute__((address_space(1))) const void global_cvoid;
typedef __attribute__((address_space(3))) void lds_void;

// ws layout (bytes)
#define AC_OFF   0u                           // fp16 chunks [b][kc(32)][n(4096)] * 16B = 8MB
#define BC_OFF   (8u << 20)                   // same, 8MB
#define A2_OFF   (16u << 20)                  // f32 [b][n]  a2 + 2eps*sa            (64KB)
#define B2_OFF   ((16u << 20) + (64u << 10))  // f32 [b][n]  b2 - 2eps*sb + C*eps^2  (64KB)
#define DP_OFF   ((16u << 20) + (128u << 10)) // f32 [b][n][4] per-mq min d2         (256KB)
#define WS_TOTAL ((16u << 20) + (384u << 10))

// ---------------------------------------------------------------- gather
// grid (64 h, 4 b, 2 input), block 256.  (at the 128MB-line fetch floor)
__global__ __launch_bounds__(256) void gm_gather(
    const float* __restrict__ srcA, const float* __restrict__ srcB,
    unsigned char* __restrict__ ws)
{
  const int t  = threadIdx.x;
  const int h  = blockIdx.x;
  const int b  = blockIdx.y;
  const int z  = blockIdx.z;               // 0 -> a, 1 -> b
  const int w  = t & 63;
  const int wv = t >> 6;

  const float* src = z ? srcB : srcA;
  unsigned char* dst = ws + (z ? BC_OFF : AC_OFF);
  float* norms = (float*)(ws + (z ? B2_OFF : A2_OFF));
  const float epsSign = z ? -2.0f * EPSV : 2.0f * EPSV;
  const float addC    = z ? (float)CH * EPSV * EPSV : 0.0f;

  const float* rowbase = src + ((size_t)b * CH) * (HH * WW)
                             + (size_t)(h * 4) * WW + (size_t)(w * 4);
  float ssum = 0.0f, ssq = 0.0f;
  #pragma unroll
  for (int i = 0; i < 8; ++i) {
    const int kc = wv * 8 + i;             // 16B chunk index (8 channels)
    half8 hv;
    #pragma unroll
    for (int j = 0; j < 8; ++j) {
      const int c = kc * 8 + j;
      float v = rowbase[(size_t)c * (HH * WW)];
      ssum += v;
      ssq  = fmaf(v, v, ssq);
      hv[j] = (_Float16)v;
    }
    *reinterpret_cast<half8*>(dst + ((size_t)((b * 32 + kc) * NPTS + h * 64 + w)) * 16) = hv;
  }

  __shared__ float red[2][4][64];
  red[0][wv][w] = ssum;
  red[1][wv][w] = ssq;
  __syncthreads();
  if (t < 64) {
    float sm = red[0][0][t] + red[0][1][t] + red[0][2][t] + red[0][3][t];
    float sq = red[1][0][t] + red[1][1][t] + red[1][2][t] + red[1][3][t];
    norms[b * NPTS + h * 64 + t] = fmaf(epsSign, sm, sq) + addC;
  }
}

// ---------------------------------------------------------------- gemm + min
// grid 512 (XCD-chunk swizzled -> 2 independent blocks/CU), block 256 (4 waves).
// Block: 128 n x 1024 m, K=256. A strip (128x256 fp16 = 64KB) staged once
// through the full LDS, wave wv extracts its 32 n-rows into af[2][8] (64 VGPR).
// B streamed as 64m x 256K (32KB) tiles, double-buffered in the same 64KB,
// counted vmcnt(8). XOR swizzle byte ^= ((row&7)<<4) applied to the FULL
// offset on BOTH the global_load_lds source side and every ds_read.
// MFMA 16x16x32_f16 C/D: col=lane&15, row=(lane>>4)*4+reg.
__device__ __forceinline__ void stage_b_tile(const unsigned char* __restrict__ Bc,
                                             int b, int mbase,
                                             unsigned char* dst, int t) {
  const int wv = t >> 6;
  #pragma unroll
  for (int r = 0; r < 8; ++r) {
    unsigned x  = (unsigned)(r * 256 + t) * 16;            // dest byte in 32KB tile
    unsigned lb = x ^ (((x >> 9) & 7) << 4);               // logical byte
    unsigned m_l = lb >> 9;                                // 0..63
    unsigned kcb = (lb & 511) >> 4;                        // 0..31
    const unsigned char* srcp =
        Bc + ((size_t)((b * 32 + kcb) * NPTS + mbase + m_l)) * 16;
    __builtin_amdgcn_global_load_lds((global_cvoid*)srcp,
                                     (lds_void*)(dst + (r * 4096 + wv * 1024)),
                                     16, 0, 0);
  }
}

__global__ __launch_bounds__(256, 2) void gm_gemm_min(
    const unsigned char* __restrict__ Ac, const unsigned char* __restrict__ Bc,
    const float* __restrict__ a2p, const float* __restrict__ b2pc,
    float* __restrict__ d2part)
{
  __shared__ __align__(16) unsigned char smem[65536];

  const int t  = threadIdx.x;
  const int l  = t & 63;
  const int wv = t >> 6;                   // 0..3 (wave owns 32 n-rows)
  const int q  = (l >> 4) & 3;

  // bijective XCD-chunk swizzle (512 blocks, 8 XCDs, 64 per chunk)
  const int orig    = blockIdx.x;
  const int logical = (orig & 7) * 64 + (orig >> 3);
  const int ns = logical & 31;             // 32 n-strips of 128
  const int mq = (logical >> 5) & 3;       // 4 m-quarters
  const int b  = logical >> 7;             // 4 batches
  const int nbase  = ns * 128;
  const int mstart = mq * 1024;

  // ---- stage A strip (128 rows x 256 K fp16 = 64KB) into full LDS
  #pragma unroll
  for (int r = 0; r < 16; ++r) {
    unsigned x  = (unsigned)(r * 256 + t) * 16;
    unsigned lb = x ^ (((x >> 9) & 7) << 4);
    unsigned n_l = lb >> 9;                                // 0..127
    unsigned kcb = (lb & 511) >> 4;
    const unsigned char* srcp =
        Ac + ((size_t)((b * 32 + kcb) * NPTS + nbase + n_l)) * 16;
    __builtin_amdgcn_global_load_lds((global_cvoid*)srcp,
                                     (lds_void*)(smem + (r * 4096 + wv * 1024)),
                                     16, 0, 0);
  }
  asm volatile("s_waitcnt vmcnt(0)" ::: "memory");
  __builtin_amdgcn_s_barrier();

  // ---- A fragments: wave's 32 n-rows, full K=256 (64 VGPRs)
  half8 af[2][8];
  #pragma unroll
  for (int nf = 0; nf < 2; ++nf) {
    const unsigned rr = wv * 32 + nf * 16 + (l & 15);
    const unsigned sw = (rr & 7) << 4;
    #pragma unroll
    for (int kk = 0; kk < 8; ++kk)
      af[nf][kk] = *reinterpret_cast<const half8*>(
          smem + ((rr * 512 + q * 16 + kk * 64) ^ sw));
  }
  asm volatile("s_waitcnt lgkmcnt(0)" ::: "memory");
  __builtin_amdgcn_s_barrier();

  float rmin[2][4];
  #pragma unroll
  for (int nf = 0; nf < 2; ++nf)
    #pragma unroll
    for (int r = 0; r < 4; ++r) rmin[nf][r] = 3.0e38f;

  // ---- main loop: 16 B-tiles of 64 m, double-buffered, counted vmcnt
  stage_b_tile(Bc, b, mstart, smem, t);                    // tile 0 -> buf0
  for (int mt = 0; mt < 16; ++mt) {
    unsigned char* cb = (mt & 1) ? smem + 32768 : smem;    // compute buffer
    unsigned char* nb = (mt & 1) ? smem : smem + 32768;    // prefetch buffer
    if (mt < 15) {
      stage_b_tile(Bc, b, mstart + (mt + 1) * 64, nb, t);
      asm volatile("s_waitcnt vmcnt(8)" ::: "memory");     // tile mt landed
    } else {
      asm volatile("s_waitcnt vmcnt(0)" ::: "memory");
    }
    __builtin_amdgcn_s_barrier();

    f32x4 acc[2][4];
    #pragma unroll
    for (int nf = 0; nf < 2; ++nf)
      #pragma unroll
      for (int ms = 0; ms < 4; ++ms) acc[nf][ms] = (f32x4){0.f, 0.f, 0.f, 0.f};

    #pragma unroll
    for (int kk = 0; kk < 8; ++kk) {
      half8 bf[4];
      #pragma unroll
      for (int ms = 0; ms < 4; ++ms) {
        const unsigned rrB = ms * 16 + (l & 15);
        bf[ms] = *reinterpret_cast<const half8*>(
            cb + ((rrB * 512 + q * 16 + kk * 64) ^ ((rrB & 7) << 4)));
      }
      #pragma unroll
      for (int ms = 0; ms < 4; ++ms) {
        acc[0][ms] = __builtin_amdgcn_mfma_f32_16x16x32_f16(af[0][kk], bf[ms], acc[0][ms], 0, 0, 0);
        acc[1][ms] = __builtin_amdgcn_mfma_f32_16x16x32_f16(af[1][kk], bf[ms], acc[1][ms], 0, 0, 0);
      }
    }

    const int mbase = mstart + mt * 64;
    #pragma unroll
    for (int ms = 0; ms < 4; ++ms) {
      const float bp = b2pc[b * NPTS + mbase + ms * 16 + (l & 15)];
      #pragma unroll
      for (int r = 0; r < 4; ++r) {
        rmin[0][r] = fminf(rmin[0][r], fmaf(-2.0f, acc[0][ms][r], bp));
        rmin[1][r] = fminf(rmin[1][r], fmaf(-2.0f, acc[1][ms][r], bp));
      }
    }
    __builtin_amdgcn_s_barrier();          // cb fully consumed before restage
  }

  // ---- reduce over the 16 col-lanes (m), add a2 term, write per-mq min
  #pragma unroll
  for (int nf = 0; nf < 2; ++nf)
    #pragma unroll
    for (int r = 0; r < 4; ++r) {
      float v = rmin[nf][r];
      v = fminf(v, __shfl_xor(v, 1, 64));
      v = fminf(v, __shfl_xor(v, 2, 64));
      v = fminf(v, __shfl_xor(v, 4, 64));
      v = fminf(v, __shfl_xor(v, 8, 64));
      if ((l & 15) == 0) {
        const int n = nbase + wv * 32 + nf * 16 + q * 4 + r;
        d2part[(size_t)(b * NPTS + n) * 4 + mq] = v + a2p[b * NPTS + n];
      }
    }
}

// ---------------------------------------------------------------- finalize
__global__ __launch_bounds__(256) void gm_finalize(
    const float* __restrict__ d2part, float* __restrict__ out)
{
  const int id = blockIdx.x * 256 + threadIdx.x;      // 0..16383  (b*4096 + n)
  const f32x4 u = *reinterpret_cast<const f32x4*>(d2part + (size_t)id * 4);
  const float d2 = fminf(fminf(u[0], u[1]), fminf(u[2], u[3]));
  const float l2 = sqrtf(fmaxf(d2, 0.0f));
  const float s  = 2.0f / (1.0f + expf(l2));          // 2*sigmoid(-l2)
  const int b = id >> 12;
  const int n = id & 4095;
  const int h = n >> 6, w = n & 63;
  float4 v = make_float4(s, s, s, s);
  float* obase = out + ((size_t)(b * 256 + h * 4)) * 256 + w * 4;
  #pragma unroll
  for (int i = 0; i < 4; ++i)
    *reinterpret_cast<float4*>(obase + (size_t)i * 256) = v;
}

__global__ void gm_sentinel(float* out) { out[0] = 1.0e6f; }

extern "C" void kernel_launch(void* const* d_in, const int* in_sizes, int n_in,
                              void* d_out, int out_size, void* d_ws, size_t ws_size,
                              hipStream_t stream) {
  const float* a = (const float*)d_in[0];
  const float* b = (const float*)d_in[1];
  float* out = (float*)d_out;
  unsigned char* ws = (unsigned char*)d_ws;

  if (ws_size < (size_t)WS_TOTAL) {
    gm_sentinel<<<1, 1, 0, stream>>>(out);
    return;
  }

  gm_gather<<<dim3(64, 4, 2), 256, 0, stream>>>(a, b, ws);
  gm_gemm_min<<<512, 256, 0, stream>>>(
      ws + AC_OFF, ws + BC_OFF,
      (const float*)(ws + A2_OFF), (const float*)(ws + B2_OFF),
      (float*)(ws + DP_OFF));
  gm_finalize<<<64, 256, 0, stream>>>((const float*)(ws + DP_OFF), out);
}

// Round 7
// 72.714 us; speedup vs baseline: 1.4783x; 1.0339x over previous
//
#include <hip/hip_runtime.h>
#include <math.h>

// GlobalMatch: subsample stride-4 -> per batch 4096 pts x 256 ch,
// all-pairs min distance (a vs b), score = 2*sigmoid(-sqrt(d2min)), 4x4 upsample.
//
// Pipeline: gather/compact(fp16, K-chunked layout) -> fp16 16x16x32 MFMA GEMM
// (4-deep B pipeline, counted vmcnt, 1 barrier/tile, b2 in LDS) -> finalize.

#define BATCH 4
#define CH    256
#define HH    256
#define WW    256
#define NPTS  4096          // 64*64 subsampled points per batch
#define EPSV  1e-6f

typedef _Float16 half8  __attribute__((ext_vector_type(8)));
typedef float    f32x4  __attribute__((ext_vector_type(4)));

typedef __attribute__((address_space(1))) const void global_cvoid;
typedef __attribute__((address_space(3))) void lds_void;

// ws layout (bytes)
#define AC_OFF   0u                           // fp16 chunks [b][kc(32)][n(4096)] * 16B = 8MB
#define BC_OFF   (8u << 20)                   // same, 8MB
#define A2_OFF   (16u << 20)                  // f32 [b][n]  a2 + 2eps*sa            (64KB)
#define B2_OFF   ((16u << 20) + (64u << 10))  // f32 [b][n]  b2 - 2eps*sb + C*eps^2  (64KB)
#define DP_OFF   ((16u << 20) + (128u << 10)) // f32 [b][n][4] per-mq min d2         (256KB)
#define WS_TOTAL ((16u << 20) + (384u << 10))

// ---------------------------------------------------------------- gather
// grid (64 h, 4 b, 2 input), block 256.  (at the 128MB-line fetch floor)
__global__ __launch_bounds__(256) void gm_gather(
    const float* __restrict__ srcA, const float* __restrict__ srcB,
    unsigned char* __restrict__ ws)
{
  const int t  = threadIdx.x;
  const int h  = blockIdx.x;
  const int b  = blockIdx.y;
  const int z  = blockIdx.z;               // 0 -> a, 1 -> b
  const int w  = t & 63;
  const int wv = t >> 6;

  const float* src = z ? srcB : srcA;
  unsigned char* dst = ws + (z ? BC_OFF : AC_OFF);
  float* norms = (float*)(ws + (z ? B2_OFF : A2_OFF));
  const float epsSign = z ? -2.0f * EPSV : 2.0f * EPSV;
  const float addC    = z ? (float)CH * EPSV * EPSV : 0.0f;

  const float* rowbase = src + ((size_t)b * CH) * (HH * WW)
                             + (size_t)(h * 4) * WW + (size_t)(w * 4);
  float ssum = 0.0f, ssq = 0.0f;
  #pragma unroll
  for (int i = 0; i < 8; ++i) {
    const int kc = wv * 8 + i;             // 16B chunk index (8 channels)
    half8 hv;
    #pragma unroll
    for (int j = 0; j < 8; ++j) {
      const int c = kc * 8 + j;
      float v = rowbase[(size_t)c * (HH * WW)];
      ssum += v;
      ssq  = fmaf(v, v, ssq);
      hv[j] = (_Float16)v;
    }
    *reinterpret_cast<half8*>(dst + ((size_t)((b * 32 + kc) * NPTS + h * 64 + w)) * 16) = hv;
  }

  __shared__ float red[2][4][64];
  red[0][wv][w] = ssum;
  red[1][wv][w] = ssq;
  __syncthreads();
  if (t < 64) {
    float sm = red[0][0][t] + red[0][1][t] + red[0][2][t] + red[0][3][t];
    float sq = red[1][0][t] + red[1][1][t] + red[1][2][t] + red[1][3][t];
    norms[b * NPTS + h * 64 + t] = fmaf(epsSign, sm, sq) + addC;
  }
}

// ---------------------------------------------------------------- gemm + min
// grid 256 (XCD-chunk swizzled), block 512 (8 waves, 1 block/CU via 132KB LDS).
// Block: 256 n x 1024 m, K=256. A strip (256x512B = 128KB) staged once through
// all of smem; wave wv extracts its 32 n-rows into af[2][8] (64 VGPR).
// B streamed as 64m x 256K (32KB) tiles through FOUR buffers (prefetch depth
// 3): per tile  [vmcnt(8) -> s_barrier -> issue stage(mt+3) -> compute(mt)].
// Steady-state vmcnt(8) = tiles mt+1,mt+2 in flight (4 loads each), never 0.
// b2 values live in LDS (sB2) so the main loop has NO vmem besides staging
// (keeps the vmcnt counting exact - no compiler drains).
// XOR swizzle byte ^= ((row&7)<<4) on FULL offsets, BOTH sides (stage source
// pre-swizzled, ds_read swizzled).
// MFMA 16x16x32_f16 C/D: col=lane&15, row=(lane>>4)*4+reg.
__device__ __forceinline__ void stage_b_tile(const unsigned char* __restrict__ Bc,
                                             int b, int mbase,
                                             unsigned char* dst, int t) {
  const int wv = t >> 6;
  #pragma unroll
  for (int r = 0; r < 4; ++r) {
    unsigned x  = (unsigned)(r * 512 + t) * 16;            // dest byte in 32KB tile
    unsigned lb = x ^ (((x >> 9) & 7) << 4);               // logical byte
    unsigned m_l = lb >> 9;                                // 0..63
    unsigned kcb = (lb & 511) >> 4;                        // 0..31
    const unsigned char* srcp =
        Bc + ((size_t)((b * 32 + kcb) * NPTS + mbase + m_l)) * 16;
    __builtin_amdgcn_global_load_lds((global_cvoid*)srcp,
                                     (lds_void*)(dst + (r * 8192 + wv * 1024)),
                                     16, 0, 0);
  }
}

__global__ __launch_bounds__(512, 2) void gm_gemm_min(
    const unsigned char* __restrict__ Ac, const unsigned char* __restrict__ Bc,
    const float* __restrict__ a2p, const float* __restrict__ b2pc,
    float* __restrict__ d2part)
{
  __shared__ __align__(16) unsigned char smem[131072];     // A stage / 4 B buffers
  __shared__ float sB2[1024];                              // b2 for this m-quarter

  const int t  = threadIdx.x;
  const int l  = t & 63;
  const int wv = t >> 6;                   // 0..7 (wave owns 32 n-rows)
  const int q  = (l >> 4) & 3;

  // bijective XCD-chunk swizzle (256 blocks, 8 XCDs, 32 per chunk)
  const int orig    = blockIdx.x;
  const int logical = (orig & 7) * 32 + (orig >> 3);
  const int ns = logical & 15;             // 16 n-strips of 256
  const int mq = (logical >> 4) & 3;       // 4 m-quarters
  const int b  = logical >> 6;             // 4 batches
  const int nbase  = ns * 256;
  const int mstart = mq * 1024;

  // ---- stage A strip (256 rows x 256 K fp16 = 128KB) into all of smem
  #pragma unroll
  for (int r = 0; r < 16; ++r) {
    unsigned x  = (unsigned)(r * 512 + t) * 16;
    unsigned lb = x ^ (((x >> 9) & 7) << 4);
    unsigned n_l = lb >> 9;                                // 0..255
    unsigned kcb = (lb & 511) >> 4;
    const unsigned char* srcp =
        Ac + ((size_t)((b * 32 + kcb) * NPTS + nbase + n_l)) * 16;
    __builtin_amdgcn_global_load_lds((global_cvoid*)srcp,
                                     (lds_void*)(smem + (r * 8192 + wv * 1024)),
                                     16, 0, 0);
  }
  // b2 quarter-panel into LDS (1024 floats)
  sB2[t]       = b2pc[b * NPTS + mstart + t];
  sB2[t + 512] = b2pc[b * NPTS + mstart + t + 512];

  asm volatile("s_waitcnt vmcnt(0) lgkmcnt(0)" ::: "memory");
  __builtin_amdgcn_s_barrier();

  // ---- A fragments: wave's 32 n-rows, full K=256 (64 VGPRs)
  half8 af[2][8];
  #pragma unroll
  for (int nf = 0; nf < 2; ++nf) {
    const unsigned rr = wv * 32 + nf * 16 + (l & 15);
    const unsigned sw = (rr & 7) << 4;
    #pragma unroll
    for (int kk = 0; kk < 8; ++kk)
      af[nf][kk] = *reinterpret_cast<const half8*>(
          smem + ((rr * 512 + q * 16 + kk * 64) ^ sw));
  }
  asm volatile("s_waitcnt lgkmcnt(0)" ::: "memory");
  __builtin_amdgcn_s_barrier();

  float rmin[2][4];
  #pragma unroll
  for (int nf = 0; nf < 2; ++nf)
    #pragma unroll
    for (int r = 0; r < 4; ++r) rmin[nf][r] = 3.0e38f;

  // ---- prologue: prefetch tiles 0,1,2 into buffers 0,1,2
  stage_b_tile(Bc, b, mstart +   0, smem,          t);
  stage_b_tile(Bc, b, mstart +  64, smem + 32768,  t);
  stage_b_tile(Bc, b, mstart + 128, smem + 65536,  t);

  // ---- main loop: 16 B-tiles of 64 m, prefetch depth 3, 1 barrier/tile
  for (int mt = 0; mt < 16; ++mt) {
    if (mt <= 13)      asm volatile("s_waitcnt vmcnt(8)" ::: "memory");
    else if (mt == 14) asm volatile("s_waitcnt vmcnt(4)" ::: "memory");
    else               asm volatile("s_waitcnt vmcnt(0)" ::: "memory");
    __builtin_amdgcn_s_barrier();

    if (mt <= 12)
      stage_b_tile(Bc, b, mstart + (mt + 3) * 64,
                   smem + (unsigned)((mt + 3) & 3) * 32768, t);

    const unsigned char* cb = smem + (unsigned)(mt & 3) * 32768;

    f32x4 acc[2][4];
    #pragma unroll
    for (int nf = 0; nf < 2; ++nf)
      #pragma unroll
      for (int ms = 0; ms < 4; ++ms) acc[nf][ms] = (f32x4){0.f, 0.f, 0.f, 0.f};

    __builtin_amdgcn_s_setprio(1);
    #pragma unroll
    for (int kk = 0; kk < 8; ++kk) {
      half8 bf[4];
      #pragma unroll
      for (int ms = 0; ms < 4; ++ms) {
        const unsigned rrB = ms * 16 + (l & 15);
        bf[ms] = *reinterpret_cast<const half8*>(
            cb + ((rrB * 512 + q * 16 + kk * 64) ^ ((rrB & 7) << 4)));
      }
      #pragma unroll
      for (int ms = 0; ms < 4; ++ms) {
        acc[0][ms] = __builtin_amdgcn_mfma_f32_16x16x32_f16(af[0][kk], bf[ms], acc[0][ms], 0, 0, 0);
        acc[1][ms] = __builtin_amdgcn_mfma_f32_16x16x32_f16(af[1][kk], bf[ms], acc[1][ms], 0, 0, 0);
      }
    }
    __builtin_amdgcn_s_setprio(0);

    #pragma unroll
    for (int ms = 0; ms < 4; ++ms) {
      const float bp = sB2[mt * 64 + ms * 16 + (l & 15)];
      #pragma unroll
      for (int r = 0; r < 4; ++r) {
        rmin[0][r] = fminf(rmin[0][r], fmaf(-2.0f, acc[0][ms][r], bp));
        rmin[1][r] = fminf(rmin[1][r], fmaf(-2.0f, acc[1][ms][r], bp));
      }
    }
  }

  // ---- reduce over the 16 col-lanes (m), add a2 term, write per-mq min
  #pragma unroll
  for (int nf = 0; nf < 2; ++nf)
    #pragma unroll
    for (int r = 0; r < 4; ++r) {
      float v = rmin[nf][r];
      v = fminf(v, __shfl_xor(v, 1, 64));
      v = fminf(v, __shfl_xor(v, 2, 64));
      v = fminf(v, __shfl_xor(v, 4, 64));
      v = fminf(v, __shfl_xor(v, 8, 64));
      if ((l & 15) == 0) {
        const int n = nbase + wv * 32 + nf * 16 + q * 4 + r;
        d2part[(size_t)(b * NPTS + n) * 4 + mq] = v + a2p[b * NPTS + n];
      }
    }
}

// ---------------------------------------------------------------- finalize
__global__ __launch_bounds__(256) void gm_finalize(
    const float* __restrict__ d2part, float* __restrict__ out)
{
  const int id = blockIdx.x * 256 + threadIdx.x;      // 0..16383  (b*4096 + n)
  const f32x4 u = *reinterpret_cast<const f32x4*>(d2part + (size_t)id * 4);
  const float d2 = fminf(fminf(u[0], u[1]), fminf(u[2], u[3]));
  const float l2 = sqrtf(fmaxf(d2, 0.0f));
  const float s  = 2.0f / (1.0f + expf(l2));          // 2*sigmoid(-l2)
  const int b = id >> 12;
  const int n = id & 4095;
  const int h = n >> 6, w = n & 63;
  float4 v = make_float4(s, s, s, s);
  float* obase = out + ((size_t)(b * 256 + h * 4)) * 256 + w * 4;
  #pragma unroll
  for (int i = 0; i < 4; ++i)
    *reinterpret_cast<float4*>(obase + (size_t)i * 256) = v;
}

__global__ void gm_sentinel(float* out) { out[0] = 1.0e6f; }

extern "C" void kernel_launch(void* const* d_in, const int* in_sizes, int n_in,
                              void* d_out, int out_size, void* d_ws, size_t ws_size,
                              hipStream_t stream) {
  const float* a = (const float*)d_in[0];
  const float* b = (const float*)d_in[1];
  float* out = (float*)d_out;
  unsigned char* ws = (unsigned char*)d_ws;

  if (ws_size < (size_t)WS_TOTAL) {
    gm_sentinel<<<1, 1, 0, stream>>>(out);
    return;
  }

  gm_gather<<<dim3(64, 4, 2), 256, 0, stream>>>(a, b, ws);
  gm_gemm_min<<<256, 512, 0, stream>>>(
      ws + AC_OFF, ws + BC_OFF,
      (const float*)(ws + A2_OFF), (const float*)(ws + B2_OFF),
      (float*)(ws + DP_OFF));
  gm_finalize<<<64, 256, 0, stream>>>((const float*)(ws + DP_OFF), out);
}